// Round 1
// baseline (94.417 us; speedup 1.0000x reference)
//
#include <hip/hip_runtime.h>
#include <stdint.h>

typedef __bf16 bf16;
typedef __attribute__((ext_vector_type(8))) __bf16 bfx8;
typedef __attribute__((ext_vector_type(4))) float f32x4;

__device__ inline f32x4 mfma16(bfx8 a, bfx8 b, f32x4 c) {
  return __builtin_amdgcn_mfma_f32_16x16x32_bf16(a, b, c, 0, 0, 0);
}

// ---------------- GEMM: C[m][n] = sum_k A[m][k] * Bt[n][k] ----------------
// M = 4096 (grid.x * 128), N = 512 (grid.y * 128), K = 512, all LD = 512.
// LDS tiles are 128x64 bf16, XOR-swizzled on 16B slots: slot' = slot ^ (row&7).
struct GemmArgs {
  const void* A[3];
  const void* Bt[3];
  bf16* ob[3];
  float* of;
  int phi_upto;  // z < phi_upto applies phi = elu(x)+1
};

template <bool AF32, bool BF32, bool OUTF>
__global__ __launch_bounds__(256) void gemm_bt(GemmArgs ga) {
  const int z = blockIdx.z;
  const void* Ag = ga.A[z];
  const void* Bg = ga.Bt[z];
  const int tm = blockIdx.x * 128, tn = blockIdx.y * 128;
  const int tid = threadIdx.x, l = tid & 63, w = tid >> 6;
  const int wm = w >> 1, wn = w & 1, lm = l & 15, lk = l >> 4;

  __shared__ __align__(16) bf16 As[128 * 64];
  __shared__ __align__(16) bf16 Bs[128 * 64];

  f32x4 acc[4][4] = {};

  for (int kt = 0; kt < 8; ++kt) {
    // ---- stage A tile (128 rows x 64 k) ----
#pragma unroll
    for (int it = 0; it < 4; ++it) {
      int c = (it * 4 + w) * 64 + l;  // 16B chunk id 0..1023
      int row = c >> 3, t8 = c & 7;
      bfx8 v;
      if (AF32) {
        const float* s = (const float*)Ag + (size_t)(tm + row) * 512 + kt * 64 + t8 * 8;
        f32x4 x0 = *(const f32x4*)s;
        f32x4 x1 = *(const f32x4*)(s + 4);
        v[0] = (bf16)x0[0]; v[1] = (bf16)x0[1]; v[2] = (bf16)x0[2]; v[3] = (bf16)x0[3];
        v[4] = (bf16)x1[0]; v[5] = (bf16)x1[1]; v[6] = (bf16)x1[2]; v[7] = (bf16)x1[3];
      } else {
        v = *(const bfx8*)((const bf16*)Ag + (size_t)(tm + row) * 512 + kt * 64 + t8 * 8);
      }
      *(bfx8*)&As[row * 64 + ((t8 ^ (row & 7)) << 3)] = v;
    }
    // ---- stage B tile ----
#pragma unroll
    for (int it = 0; it < 4; ++it) {
      int c = (it * 4 + w) * 64 + l;
      int row = c >> 3, t8 = c & 7;
      bfx8 v;
      if (BF32) {
        const float* s = (const float*)Bg + (size_t)(tn + row) * 512 + kt * 64 + t8 * 8;
        f32x4 x0 = *(const f32x4*)s;
        f32x4 x1 = *(const f32x4*)(s + 4);
        v[0] = (bf16)x0[0]; v[1] = (bf16)x0[1]; v[2] = (bf16)x0[2]; v[3] = (bf16)x0[3];
        v[4] = (bf16)x1[0]; v[5] = (bf16)x1[1]; v[6] = (bf16)x1[2]; v[7] = (bf16)x1[3];
      } else {
        v = *(const bfx8*)((const bf16*)Bg + (size_t)(tn + row) * 512 + kt * 64 + t8 * 8);
      }
      *(bfx8*)&Bs[row * 64 + ((t8 ^ (row & 7)) << 3)] = v;
    }
    __syncthreads();
#pragma unroll
    for (int ks = 0; ks < 2; ++ks) {
      bfx8 af[4], bfr[4];
#pragma unroll
      for (int i = 0; i < 4; ++i) {
        int ra = wm * 64 + i * 16 + lm;
        af[i] = *(const bfx8*)&As[ra * 64 + (((ks * 4 + lk) ^ (ra & 7)) << 3)];
        int rb = wn * 64 + i * 16 + lm;
        bfr[i] = *(const bfx8*)&Bs[rb * 64 + (((ks * 4 + lk) ^ (rb & 7)) << 3)];
      }
#pragma unroll
      for (int i = 0; i < 4; ++i)
#pragma unroll
        for (int j = 0; j < 4; ++j)
          acc[i][j] = mfma16(af[i], bfr[j], acc[i][j]);
    }
    __syncthreads();
  }

  const bool phi = z < ga.phi_upto;
#pragma unroll
  for (int i = 0; i < 4; ++i)
#pragma unroll
    for (int j = 0; j < 4; ++j)
#pragma unroll
      for (int r = 0; r < 4; ++r) {
        int m = tm + wm * 64 + i * 16 + lk * 4 + r;
        int n = tn + wn * 64 + j * 16 + lm;
        float v = acc[i][j][r];
        if (phi) v = v > 0.f ? v + 1.f : __expf(v);
        if (OUTF) ga.of[(size_t)m * 512 + n] = v;
        else ga.ob[z][(size_t)m * 512 + n] = (bf16)v;
      }
}

// ---------------- causal linear attention, one block per (b,h) ----------------
// Qf,Kf,Vh,Ob are (4096 x 512) bf16 row-major; head h occupies cols [h*64, h*64+64).
// Chunked scan, chunk=64: S = Qf Kf^T (masked), out = (S~ V + Qf KV) / (den+eps),
// KV[e][d] += sum_j V[j][e] Kf[j][d]; ksum[d] += sum_j Kf[j][d].
__global__ __launch_bounds__(256) void attn_causal(const bf16* __restrict__ Qf,
                                                   const bf16* __restrict__ Kf,
                                                   const bf16* __restrict__ Vh,
                                                   bf16* __restrict__ Ob) {
  const int bh = blockIdx.x, b = bh >> 3, h = bh & 7;
  const int tid = threadIdx.x, l = tid & 63, w = tid >> 6, lm = l & 15, lk = l >> 4;

  __shared__ __align__(16) bf16 Qs[64 * 64];   // [i][d]  swizzled
  __shared__ __align__(16) bf16 Ks[64 * 64];   // [j][d]
  __shared__ __align__(16) bf16 KTs[64 * 64];  // [d][j]
  __shared__ __align__(16) bf16 VTs[64 * 64];  // [e][j]
  __shared__ __align__(16) bf16 Ss[64 * 64];   // [i][j] masked S
  __shared__ __align__(16) float KV[64 * 64];  // [e][d] fp32 state, quad-swizzled
  __shared__ float ksum[64], den_i[64], den_all[64];
  __shared__ float den_p[256], ksum_p[256];

  for (int i = tid; i < 64 * 64; i += 256) KV[i] = 0.f;
  if (tid < 64) ksum[tid] = 0.f;
  __syncthreads();

  const size_t base = (size_t)(b * 1024) * 512 + h * 64;
  const int sr = tid >> 2, sp = tid & 3;  // staging: row 0..63, 16-col part 0..3

  for (int c = 0; c < 16; ++c) {
    const int nb = c * 64;
    // ---------- stage ----------
    {
      const size_t g = base + (size_t)(nb + sr) * 512 + sp * 16;
      bfx8 q0 = *(const bfx8*)&Qf[g], q1 = *(const bfx8*)&Qf[g + 8];
      bfx8 k0 = *(const bfx8*)&Kf[g], k1 = *(const bfx8*)&Kf[g + 8];
      bfx8 v0 = *(const bfx8*)&Vh[g], v1 = *(const bfx8*)&Vh[g + 8];
      *(bfx8*)&Qs[sr * 64 + (((2 * sp) ^ (sr & 7)) << 3)] = q0;
      *(bfx8*)&Qs[sr * 64 + (((2 * sp + 1) ^ (sr & 7)) << 3)] = q1;
      *(bfx8*)&Ks[sr * 64 + (((2 * sp) ^ (sr & 7)) << 3)] = k0;
      *(bfx8*)&Ks[sr * 64 + (((2 * sp + 1) ^ (sr & 7)) << 3)] = k1;
#pragma unroll
      for (int q = 0; q < 8; ++q) {
        int d0 = sp * 16 + q, d1 = sp * 16 + 8 + q;
        KTs[d0 * 64 + (((sr >> 3) ^ (d0 & 7)) << 3) + (sr & 7)] = k0[q];
        KTs[d1 * 64 + (((sr >> 3) ^ (d1 & 7)) << 3) + (sr & 7)] = k1[q];
        VTs[d0 * 64 + (((sr >> 3) ^ (d0 & 7)) << 3) + (sr & 7)] = v0[q];
        VTs[d1 * 64 + (((sr >> 3) ^ (d1 & 7)) << 3) + (sr & 7)] = v1[q];
      }
    }
    __syncthreads();
    // ---------- phase A: S, mask, rowsum, den partials ----------
    f32x4 sacc[4] = {};
    bfx8 aq[2];
#pragma unroll
    for (int ks = 0; ks < 2; ++ks) {
      int r = w * 16 + lm;
      aq[ks] = *(const bfx8*)&Qs[r * 64 + (((ks * 4 + lk) ^ (r & 7)) << 3)];
#pragma unroll
      for (int bn = 0; bn < 4; ++bn) {
        int rb = bn * 16 + lm;
        bfx8 bk = *(const bfx8*)&Ks[rb * 64 + (((ks * 4 + lk) ^ (rb & 7)) << 3)];
        sacc[bn] = mfma16(aq[ks], bk, sacc[bn]);
      }
    }
    float prs[4] = {0.f, 0.f, 0.f, 0.f};
#pragma unroll
    for (int bn = 0; bn < 4; ++bn)
#pragma unroll
      for (int rg = 0; rg < 4; ++rg) {
        int i = w * 16 + lk * 4 + rg, j = bn * 16 + lm;
        float v = (j <= i) ? sacc[bn][rg] : 0.f;
        prs[rg] += v;
        Ss[i * 64 + (((j >> 3) ^ (i & 7)) << 3) + (j & 7)] = (bf16)v;
      }
#pragma unroll
    for (int m = 1; m < 16; m <<= 1) {
#pragma unroll
      for (int rg = 0; rg < 4; ++rg) prs[rg] += __shfl_xor(prs[rg], m, 64);
    }
    if (lm == 0) {
#pragma unroll
      for (int rg = 0; rg < 4; ++rg) den_i[w * 16 + lk * 4 + rg] = prs[rg];
    }
    {  // den_p = qf . ksum_prev (per row, 4 partials)
      float s = 0.f;
#pragma unroll
      for (int q = 0; q < 16; ++q) {
        int d = sp * 16 + q;
        s += (float)Qs[sr * 64 + (((d >> 3) ^ (sr & 7)) << 3) + (d & 7)] * ksum[d];
      }
      den_p[sp * 64 + sr] = s;
    }
    __syncthreads();
    // ---------- phase B: den finalize, ksum partials, num MFMAs, state MFMAs ----------
    if (tid < 64)
      den_all[tid] = den_i[tid] + den_p[tid] + den_p[64 + tid] + den_p[128 + tid] + den_p[192 + tid];
    {
      int d = tid & 63, jp = tid >> 6;
      float s = 0.f;
#pragma unroll
      for (int q = 0; q < 16; ++q) {
        int j = jp * 16 + q;
        s += (float)KTs[d * 64 + (((j >> 3) ^ (d & 7)) << 3) + (j & 7)];
      }
      ksum_p[jp * 64 + d] = s;
    }
    f32x4 oacc[4] = {};
    f32x4 kacc[4] = {};
#pragma unroll
    for (int ks = 0; ks < 2; ++ks) {
      int r = w * 16 + lm;
      bfx8 as_ = *(const bfx8*)&Ss[r * 64 + (((ks * 4 + lk) ^ (r & 7)) << 3)];
      bfx8 av = *(const bfx8*)&VTs[r * 64 + (((ks * 4 + lk) ^ (r & 7)) << 3)];
#pragma unroll
      for (int bn = 0; bn < 4; ++bn) {
        int e = bn * 16 + lm;
        bfx8 bv = *(const bfx8*)&VTs[e * 64 + (((ks * 4 + lk) ^ (e & 7)) << 3)];
        oacc[bn] = mfma16(as_, bv, oacc[bn]);  // intra: S~ @ V
        int d0 = ks * 32 + lk * 8;
        f32x4 x0 = *(const f32x4*)&KV[e * 64 + ((((d0 >> 2)) ^ ((e & 7) << 1)) << 2)];
        f32x4 x1 = *(const f32x4*)&KV[e * 64 + ((((d0 >> 2) + 1) ^ ((e & 7) << 1)) << 2)];
        bfx8 bkv;
        bkv[0] = (bf16)x0[0]; bkv[1] = (bf16)x0[1]; bkv[2] = (bf16)x0[2]; bkv[3] = (bf16)x0[3];
        bkv[4] = (bf16)x1[0]; bkv[5] = (bf16)x1[1]; bkv[6] = (bf16)x1[2]; bkv[7] = (bf16)x1[3];
        oacc[bn] = mfma16(aq[ks], bkv, oacc[bn]);  // inter: Qf @ KV
        bfx8 bk2 = *(const bfx8*)&KTs[e * 64 + (((ks * 4 + lk) ^ (e & 7)) << 3)];
        kacc[bn] = mfma16(av, bk2, kacc[bn]);  // dKV^T[e][d] = sum_j V^T[e][j] Kf[j][d]
      }
    }
    __syncthreads();
    // ---------- phase C: epilogue + state update ----------
#pragma unroll
    for (int bn = 0; bn < 4; ++bn)
#pragma unroll
      for (int rg = 0; rg < 4; ++rg) {
        int i = w * 16 + lk * 4 + rg, e = bn * 16 + lm;
        float o = oacc[bn][rg] / (den_all[i] + 1e-6f);
        Ob[base + (size_t)(nb + i) * 512 + e] = (bf16)o;
        int ke = w * 16 + lk * 4 + rg, kd = bn * 16 + lm;
        KV[ke * 64 + ((((kd >> 2)) ^ ((ke & 7) << 1)) << 2) + (kd & 3)] += kacc[bn][rg];
      }
    if (tid < 64)
      ksum[tid] += ksum_p[tid] + ksum_p[64 + tid] + ksum_p[128 + tid] + ksum_p[192 + tid];
    __syncthreads();
  }
}

// ---------------- launch ----------------
extern "C" void kernel_launch(void* const* d_in, const int* in_sizes, int n_in,
                              void* d_out, int out_size, void* d_ws, size_t ws_size,
                              hipStream_t stream) {
  const float* Q = (const float*)d_in[0];
  const float* K = (const float*)d_in[1];
  const float* V = (const float*)d_in[2];
  const float* Wq = (const float*)d_in[3];
  const float* Wk = (const float*)d_in[4];
  const float* Wv = (const float*)d_in[5];
  const float* Wo = (const float*)d_in[6];
  (void)in_sizes; (void)n_in; (void)out_size; (void)ws_size;

  char* wsp = (char*)d_ws;
  const size_t MB = 1ull << 20;
  bf16* Qp = (bf16*)(wsp + 0 * MB);   // 4096x512 bf16, phi(Q @ Wq^T)
  bf16* Kp = (bf16*)(wsp + 4 * MB);   // phi(K @ Wk^T)
  bf16* Vp = (bf16*)(wsp + 8 * MB);   // V @ Wv^T
  bf16* Ob = (bf16*)(wsp + 12 * MB);  // attention output (pre-Wo)

  GemmArgs g1;
  g1.A[0] = Q;  g1.A[1] = K;  g1.A[2] = V;
  g1.Bt[0] = Wq; g1.Bt[1] = Wk; g1.Bt[2] = Wv;
  g1.ob[0] = Qp; g1.ob[1] = Kp; g1.ob[2] = Vp;
  g1.of = nullptr;
  g1.phi_upto = 2;
  gemm_bt<true, true, false><<<dim3(32, 4, 3), 256, 0, stream>>>(g1);

  attn_causal<<<dim3(32), 256, 0, stream>>>(Qp, Kp, Vp, Ob);

  GemmArgs g2;
  g2.A[0] = Ob; g2.A[1] = nullptr; g2.A[2] = nullptr;
  g2.Bt[0] = Wo; g2.Bt[1] = nullptr; g2.Bt[2] = nullptr;
  g2.ob[0] = nullptr; g2.ob[1] = nullptr; g2.ob[2] = nullptr;
  g2.of = (float*)d_out;
  g2.phi_upto = 0;
  gemm_bt<false, true, true><<<dim3(32, 4, 1), 256, 0, stream>>>(g2);
}

// Round 2
// 54.139 us; speedup vs baseline: 1.7440x; 1.7440x over previous
//
#include <hip/hip_runtime.h>
#include <stdint.h>

typedef __bf16 bf16;
typedef __attribute__((ext_vector_type(8))) __bf16 bfx8;
typedef __attribute__((ext_vector_type(4))) float f32x4;

__device__ inline f32x4 mfma16(bfx8 a, bfx8 b, f32x4 c) {
  return __builtin_amdgcn_mfma_f32_16x16x32_bf16(a, b, c, 0, 0, 0);
}

// ---------------- GEMM: C[m][n] = sum_k A[m][k] * Bt[n][k] ----------------
struct GemmArgs {
  const void* A[3];
  const void* Bt[3];
  bf16* ob[3];
  float* of;
  int phi_upto;  // z < phi_upto applies phi = elu(x)+1
};

template <bool AF32, bool BF32, bool OUTF>
__global__ __launch_bounds__(256) void gemm_bt(GemmArgs ga) {
  const int z = blockIdx.z;
  const void* Ag = ga.A[z];
  const void* Bg = ga.Bt[z];
  const int tm = blockIdx.x * 128, tn = blockIdx.y * 128;
  const int tid = threadIdx.x, l = tid & 63, w = tid >> 6;
  const int wm = w >> 1, wn = w & 1, lm = l & 15, lk = l >> 4;

  __shared__ __align__(16) bf16 As[128 * 64];
  __shared__ __align__(16) bf16 Bs[128 * 64];

  f32x4 acc[4][4] = {};

  for (int kt = 0; kt < 8; ++kt) {
#pragma unroll
    for (int it = 0; it < 4; ++it) {
      int c = (it * 4 + w) * 64 + l;
      int row = c >> 3, t8 = c & 7;
      bfx8 v;
      if (AF32) {
        const float* s = (const float*)Ag + (size_t)(tm + row) * 512 + kt * 64 + t8 * 8;
        f32x4 x0 = *(const f32x4*)s;
        f32x4 x1 = *(const f32x4*)(s + 4);
        v[0] = (bf16)x0[0]; v[1] = (bf16)x0[1]; v[2] = (bf16)x0[2]; v[3] = (bf16)x0[3];
        v[4] = (bf16)x1[0]; v[5] = (bf16)x1[1]; v[6] = (bf16)x1[2]; v[7] = (bf16)x1[3];
      } else {
        v = *(const bfx8*)((const bf16*)Ag + (size_t)(tm + row) * 512 + kt * 64 + t8 * 8);
      }
      *(bfx8*)&As[row * 64 + ((t8 ^ (row & 7)) << 3)] = v;
    }
#pragma unroll
    for (int it = 0; it < 4; ++it) {
      int c = (it * 4 + w) * 64 + l;
      int row = c >> 3, t8 = c & 7;
      bfx8 v;
      if (BF32) {
        const float* s = (const float*)Bg + (size_t)(tn + row) * 512 + kt * 64 + t8 * 8;
        f32x4 x0 = *(const f32x4*)s;
        f32x4 x1 = *(const f32x4*)(s + 4);
        v[0] = (bf16)x0[0]; v[1] = (bf16)x0[1]; v[2] = (bf16)x0[2]; v[3] = (bf16)x0[3];
        v[4] = (bf16)x1[0]; v[5] = (bf16)x1[1]; v[6] = (bf16)x1[2]; v[7] = (bf16)x1[3];
      } else {
        v = *(const bfx8*)((const bf16*)Bg + (size_t)(tn + row) * 512 + kt * 64 + t8 * 8);
      }
      *(bfx8*)&Bs[row * 64 + ((t8 ^ (row & 7)) << 3)] = v;
    }
    __syncthreads();
#pragma unroll
    for (int ks = 0; ks < 2; ++ks) {
      bfx8 af[4], bfr[4];
#pragma unroll
      for (int i = 0; i < 4; ++i) {
        int ra = wm * 64 + i * 16 + lm;
        af[i] = *(const bfx8*)&As[ra * 64 + (((ks * 4 + lk) ^ (ra & 7)) << 3)];
        int rb = wn * 64 + i * 16 + lm;
        bfr[i] = *(const bfx8*)&Bs[rb * 64 + (((ks * 4 + lk) ^ (rb & 7)) << 3)];
      }
#pragma unroll
      for (int i = 0; i < 4; ++i)
#pragma unroll
        for (int j = 0; j < 4; ++j)
          acc[i][j] = mfma16(af[i], bfr[j], acc[i][j]);
    }
    __syncthreads();
  }

  const bool phi = z < ga.phi_upto;
#pragma unroll
  for (int i = 0; i < 4; ++i)
#pragma unroll
    for (int j = 0; j < 4; ++j)
#pragma unroll
      for (int r = 0; r < 4; ++r) {
        int m = tm + wm * 64 + i * 16 + lk * 4 + r;
        int n = tn + wn * 64 + j * 16 + lm;
        float v = acc[i][j][r];
        if (phi) v = v > 0.f ? v + 1.f : __expf(v);
        if (OUTF) ga.of[(size_t)m * 512 + n] = v;
        else ga.ob[z][(size_t)m * 512 + n] = (bf16)v;
      }
}

// ---------------- attention stage 1: per-chunk KV^T + ksum ----------------
// KVs[bh][c][e][d] = sum_{j in chunk c} V[j][e] * Kf[j][d]   (fp32, 64x64)
// ksums[bh][c][d]  = sum_{j in chunk c} Kf[j][d]
__global__ __launch_bounds__(256) void chunk_kv(const bf16* __restrict__ Kf,
                                                const bf16* __restrict__ Vh,
                                                float* __restrict__ KVs,
                                                float* __restrict__ ksums) {
  const int bh = blockIdx.x, c = blockIdx.y, b = bh >> 3, h = bh & 7;
  const int tid = threadIdx.x, l = tid & 63, w = tid >> 6, lm = l & 15, lk = l >> 4;
  __shared__ __align__(16) bf16 KTs[64 * 64];  // [d][j] swizzled
  __shared__ __align__(16) bf16 VTs[64 * 64];  // [e][j] swizzled
  __shared__ float ksum_p[256];

  const size_t base = (size_t)(b * 1024) * 512 + h * 64;
  const int sr = tid >> 2, sp = tid & 3;
  {
    const size_t g = base + (size_t)(c * 64 + sr) * 512 + sp * 16;
    bfx8 k0 = *(const bfx8*)&Kf[g], k1 = *(const bfx8*)&Kf[g + 8];
    bfx8 v0 = *(const bfx8*)&Vh[g], v1 = *(const bfx8*)&Vh[g + 8];
#pragma unroll
    for (int q = 0; q < 8; ++q) {
      int d0 = sp * 16 + q, d1 = sp * 16 + 8 + q;
      KTs[d0 * 64 + (((sr >> 3) ^ (d0 & 7)) << 3) + (sr & 7)] = k0[q];
      KTs[d1 * 64 + (((sr >> 3) ^ (d1 & 7)) << 3) + (sr & 7)] = k1[q];
      VTs[d0 * 64 + (((sr >> 3) ^ (d0 & 7)) << 3) + (sr & 7)] = v0[q];
      VTs[d1 * 64 + (((sr >> 3) ^ (d1 & 7)) << 3) + (sr & 7)] = v1[q];
    }
  }
  __syncthreads();
  {
    int d = tid & 63, jp = tid >> 6;
    float s = 0.f;
#pragma unroll
    for (int q = 0; q < 16; ++q) {
      int j = jp * 16 + q;
      s += (float)KTs[d * 64 + (((j >> 3) ^ (d & 7)) << 3) + (j & 7)];
    }
    ksum_p[jp * 64 + d] = s;
  }
  f32x4 kacc[4] = {};
#pragma unroll
  for (int ks = 0; ks < 2; ++ks) {
    int r = w * 16 + lm;
    bfx8 av = *(const bfx8*)&VTs[r * 64 + (((ks * 4 + lk) ^ (r & 7)) << 3)];
#pragma unroll
    for (int bn = 0; bn < 4; ++bn) {
      int e = bn * 16 + lm;
      bfx8 bk = *(const bfx8*)&KTs[e * 64 + (((ks * 4 + lk) ^ (e & 7)) << 3)];
      kacc[bn] = mfma16(av, bk, kacc[bn]);
    }
  }
  float* st = KVs + (size_t)(bh * 16 + c) * 4096;
#pragma unroll
  for (int bn = 0; bn < 4; ++bn)
#pragma unroll
    for (int rg = 0; rg < 4; ++rg) {
      int e = w * 16 + lk * 4 + rg, d = bn * 16 + lm;
      st[e * 64 + d] = kacc[bn][rg];
    }
  __syncthreads();
  if (tid < 64)
    ksums[(size_t)(bh * 16 + c) * 64 + tid] =
        ksum_p[tid] + ksum_p[64 + tid] + ksum_p[128 + tid] + ksum_p[192 + tid];
}

// ---------------- attention stage 2: exclusive prefix scan over chunks ----------------
__global__ __launch_bounds__(256) void scan_kv(float* __restrict__ KVs,
                                               float* __restrict__ ksums) {
  const int bh = blockIdx.x, slice = blockIdx.y;
  const int tid = threadIdx.x;
  float* p = KVs + (size_t)bh * 16 * 4096 + slice * 256 + tid;
  float run = 0.f;
#pragma unroll
  for (int c = 0; c < 16; ++c) {
    float t = p[(size_t)c * 4096];
    p[(size_t)c * 4096] = run;
    run += t;
  }
  if (slice == 0 && tid < 64) {
    float* kp = ksums + (size_t)bh * 16 * 64 + tid;
    float rk = 0.f;
#pragma unroll
    for (int c = 0; c < 16; ++c) {
      float t = kp[(size_t)c * 64];
      kp[(size_t)c * 64] = rk;
      rk += t;
    }
  }
}

// ---------------- attention stage 3: per-chunk output ----------------
__global__ __launch_bounds__(256) void chunk_out(const bf16* __restrict__ Qf,
                                                 const bf16* __restrict__ Kf,
                                                 const bf16* __restrict__ Vh,
                                                 const float* __restrict__ KVs,
                                                 const float* __restrict__ ksums,
                                                 bf16* __restrict__ Ob) {
  const int bh = blockIdx.x, c = blockIdx.y, b = bh >> 3, h = bh & 7;
  const int tid = threadIdx.x, l = tid & 63, w = tid >> 6, lm = l & 15, lk = l >> 4;

  __shared__ __align__(16) bf16 Qs[64 * 64];   // [i][d] swizzled
  __shared__ __align__(16) bf16 Ks[64 * 64];   // [j][d] swizzled
  __shared__ __align__(16) bf16 VTs[64 * 64];  // [e][j] swizzled
  __shared__ __align__(16) bf16 Ss[64 * 64];   // [i][j] masked S
  __shared__ float ksum[64], den_i[64], den_all[64], den_p[256];

  const size_t base = (size_t)(b * 1024) * 512 + h * 64;
  const int sr = tid >> 2, sp = tid & 3;
  {
    const size_t g = base + (size_t)(c * 64 + sr) * 512 + sp * 16;
    bfx8 q0 = *(const bfx8*)&Qf[g], q1 = *(const bfx8*)&Qf[g + 8];
    bfx8 k0 = *(const bfx8*)&Kf[g], k1 = *(const bfx8*)&Kf[g + 8];
    bfx8 v0 = *(const bfx8*)&Vh[g], v1 = *(const bfx8*)&Vh[g + 8];
    *(bfx8*)&Qs[sr * 64 + (((2 * sp) ^ (sr & 7)) << 3)] = q0;
    *(bfx8*)&Qs[sr * 64 + (((2 * sp + 1) ^ (sr & 7)) << 3)] = q1;
    *(bfx8*)&Ks[sr * 64 + (((2 * sp) ^ (sr & 7)) << 3)] = k0;
    *(bfx8*)&Ks[sr * 64 + (((2 * sp + 1) ^ (sr & 7)) << 3)] = k1;
#pragma unroll
    for (int q = 0; q < 8; ++q) {
      int d0 = sp * 16 + q, d1 = sp * 16 + 8 + q;
      VTs[d0 * 64 + (((sr >> 3) ^ (d0 & 7)) << 3) + (sr & 7)] = v0[q];
      VTs[d1 * 64 + (((sr >> 3) ^ (d1 & 7)) << 3) + (sr & 7)] = v1[q];
    }
  }
  if (tid < 64) ksum[tid] = ksums[(size_t)(bh * 16 + c) * 64 + tid];
  __syncthreads();

  // ---------- phase A: S, mask, rowsum, den partials ----------
  f32x4 sacc[4] = {};
  bfx8 aq[2];
#pragma unroll
  for (int ks = 0; ks < 2; ++ks) {
    int r = w * 16 + lm;
    aq[ks] = *(const bfx8*)&Qs[r * 64 + (((ks * 4 + lk) ^ (r & 7)) << 3)];
#pragma unroll
    for (int bn = 0; bn < 4; ++bn) {
      int rb = bn * 16 + lm;
      bfx8 bk = *(const bfx8*)&Ks[rb * 64 + (((ks * 4 + lk) ^ (rb & 7)) << 3)];
      sacc[bn] = mfma16(aq[ks], bk, sacc[bn]);
    }
  }
  float prs[4] = {0.f, 0.f, 0.f, 0.f};
#pragma unroll
  for (int bn = 0; bn < 4; ++bn)
#pragma unroll
    for (int rg = 0; rg < 4; ++rg) {
      int i = w * 16 + lk * 4 + rg, j = bn * 16 + lm;
      float v = (j <= i) ? sacc[bn][rg] : 0.f;
      prs[rg] += v;
      Ss[i * 64 + (((j >> 3) ^ (i & 7)) << 3) + (j & 7)] = (bf16)v;
    }
#pragma unroll
  for (int m = 1; m < 16; m <<= 1) {
#pragma unroll
    for (int rg = 0; rg < 4; ++rg) prs[rg] += __shfl_xor(prs[rg], m, 64);
  }
  if (lm == 0) {
#pragma unroll
    for (int rg = 0; rg < 4; ++rg) den_i[w * 16 + lk * 4 + rg] = prs[rg];
  }
  {  // den_p = Qf . ksum_prefix (per row, 4 partials)
    float s = 0.f;
#pragma unroll
    for (int q = 0; q < 16; ++q) {
      int d = sp * 16 + q;
      s += (float)Qs[sr * 64 + (((d >> 3) ^ (sr & 7)) << 3) + (d & 7)] * ksum[d];
    }
    den_p[sp * 64 + sr] = s;
  }
  __syncthreads();

  // ---------- phase B: den finalize + num MFMAs ----------
  if (tid < 64)
    den_all[tid] = den_i[tid] + den_p[tid] + den_p[64 + tid] + den_p[128 + tid] + den_p[192 + tid];
  f32x4 oacc[4] = {};
  const float* st = KVs + (size_t)(bh * 16 + c) * 4096;
#pragma unroll
  for (int ks = 0; ks < 2; ++ks) {
    int r = w * 16 + lm;
    bfx8 as_ = *(const bfx8*)&Ss[r * 64 + (((ks * 4 + lk) ^ (r & 7)) << 3)];
#pragma unroll
    for (int bn = 0; bn < 4; ++bn) {
      int e = bn * 16 + lm;
      bfx8 bv = *(const bfx8*)&VTs[e * 64 + (((ks * 4 + lk) ^ (e & 7)) << 3)];
      oacc[bn] = mfma16(as_, bv, oacc[bn]);  // intra: S~ @ V
      int d0 = ks * 32 + lk * 8;
      f32x4 x0 = *(const f32x4*)&st[e * 64 + d0];
      f32x4 x1 = *(const f32x4*)&st[e * 64 + d0 + 4];
      bfx8 bkv;
      bkv[0] = (bf16)x0[0]; bkv[1] = (bf16)x0[1]; bkv[2] = (bf16)x0[2]; bkv[3] = (bf16)x0[3];
      bkv[4] = (bf16)x1[0]; bkv[5] = (bf16)x1[1]; bkv[6] = (bf16)x1[2]; bkv[7] = (bf16)x1[3];
      oacc[bn] = mfma16(aq[ks], bkv, oacc[bn]);  // inter: Qf @ KV_prefix
    }
  }
  __syncthreads();

  // ---------- epilogue ----------
#pragma unroll
  for (int bn = 0; bn < 4; ++bn)
#pragma unroll
    for (int rg = 0; rg < 4; ++rg) {
      int i = w * 16 + lk * 4 + rg, e = bn * 16 + lm;
      float o = oacc[bn][rg] / (den_all[i] + 1e-6f);
      Ob[base + (size_t)(c * 64 + i) * 512 + e] = (bf16)o;
    }
}

// ---------------- launch ----------------
extern "C" void kernel_launch(void* const* d_in, const int* in_sizes, int n_in,
                              void* d_out, int out_size, void* d_ws, size_t ws_size,
                              hipStream_t stream) {
  const float* Q = (const float*)d_in[0];
  const float* K = (const float*)d_in[1];
  const float* V = (const float*)d_in[2];
  const float* Wq = (const float*)d_in[3];
  const float* Wk = (const float*)d_in[4];
  const float* Wv = (const float*)d_in[5];
  const float* Wo = (const float*)d_in[6];
  (void)in_sizes; (void)n_in; (void)out_size; (void)ws_size;

  char* wsp = (char*)d_ws;
  const size_t MB = 1ull << 20;
  bf16* Qp = (bf16*)(wsp + 0 * MB);    // 4096x512 bf16, phi(Q @ Wq^T)
  bf16* Kp = (bf16*)(wsp + 4 * MB);    // phi(K @ Wk^T)
  bf16* Vp = (bf16*)(wsp + 8 * MB);    // V @ Wv^T
  bf16* Ob = (bf16*)(wsp + 12 * MB);   // attention output (pre-Wo)
  float* KVs = (float*)(wsp + 16 * MB);   // 32 x 16 x 64 x 64 fp32 chunk states
  float* ksums = (float*)(wsp + 24 * MB); // 32 x 16 x 64 fp32 chunk ksums

  GemmArgs g1;
  g1.A[0] = Q;  g1.A[1] = K;  g1.A[2] = V;
  g1.Bt[0] = Wq; g1.Bt[1] = Wk; g1.Bt[2] = Wv;
  g1.ob[0] = Qp; g1.ob[1] = Kp; g1.ob[2] = Vp;
  g1.of = nullptr;
  g1.phi_upto = 2;
  gemm_bt<true, true, false><<<dim3(32, 4, 3), 256, 0, stream>>>(g1);

  chunk_kv<<<dim3(32, 16), 256, 0, stream>>>(Kp, Vp, KVs, ksums);
  scan_kv<<<dim3(32, 16), 256, 0, stream>>>(KVs, ksums);
  chunk_out<<<dim3(32, 16), 256, 0, stream>>>(Qp, Kp, Vp, KVs, ksums, Ob);

  GemmArgs g2;
  g2.A[0] = Ob; g2.A[1] = nullptr; g2.A[2] = nullptr;
  g2.Bt[0] = Wo; g2.Bt[1] = nullptr; g2.Bt[2] = nullptr;
  g2.ob[0] = nullptr; g2.ob[1] = nullptr; g2.ob[2] = nullptr;
  g2.of = (float*)d_out;
  g2.phi_upto = 0;
  gemm_bt<false, true, true><<<dim3(32, 4, 1), 256, 0, stream>>>(g2);
}